// Round 1
// baseline (265.785 us; speedup 1.0000x reference)
//
#include <hip/hip_runtime.h>
#include <math.h>

// CALayer: B=8, C=256, H=W=128, Cs=16
// out = x * sigmoid(w2 @ leakyrelu(w1 @ mean(x, HW) + b1) + b2)

#define Bn 8
#define Cn 256
#define CSn 16
#define HWn 16384          // 128*128
#define HW4 4096           // HW / 4 (float4 per plane)
#define NEG_SLOPE 0.2f

// ---------------- Kernel 1: global average pool per (b,c) plane ----------------
__global__ __launch_bounds__(256) void pool_kernel(const float* __restrict__ x,
                                                   float* __restrict__ y) {
    const int bc = blockIdx.x;                       // b*C + c
    const float4* xp = (const float4*)(x + (size_t)bc * HWn);
    float sum = 0.f;
    #pragma unroll
    for (int i = 0; i < HW4 / 256; ++i) {            // 16 float4 per thread
        float4 v = xp[threadIdx.x + i * 256];
        sum += (v.x + v.y) + (v.z + v.w);
    }
    // wave64 butterfly reduce
    #pragma unroll
    for (int off = 32; off > 0; off >>= 1)
        sum += __shfl_down(sum, off, 64);
    __shared__ float smem[4];
    const int lane = threadIdx.x & 63, wid = threadIdx.x >> 6;
    if (lane == 0) smem[wid] = sum;
    __syncthreads();
    if (threadIdx.x == 0) {
        float t = (smem[0] + smem[1]) + (smem[2] + smem[3]);
        y[bc] = t * (1.0f / (float)HWn);
    }
}

// ---------------- Kernel 2: squeeze-excite gate (tiny, one block) ----------------
__global__ __launch_bounds__(256) void gate_kernel(const float* __restrict__ y,
                                                   const float* __restrict__ w1,
                                                   const float* __restrict__ b1,
                                                   const float* __restrict__ w2,
                                                   const float* __restrict__ b2,
                                                   float* __restrict__ y2) {
    __shared__ float y1s[Bn * CSn];                  // 128 floats
    const int t = threadIdx.x;
    if (t < Bn * CSn) {
        const int b = t / CSn, s = t % CSn;
        float acc = b1[s];
        const float* yb = y + b * Cn;
        const float* ws = w1 + s * Cn;
        #pragma unroll 8
        for (int c = 0; c < Cn; ++c) acc += yb[c] * ws[c];
        y1s[t] = (acc >= 0.f) ? acc : NEG_SLOPE * acc;
    }
    __syncthreads();
    const int c = t;                                 // 256 threads == C channels
    const float* w2c = w2 + c * CSn;
    float bias = b2[c];
    #pragma unroll
    for (int b = 0; b < Bn; ++b) {
        float acc = bias;
        #pragma unroll
        for (int s = 0; s < CSn; ++s) acc += y1s[b * CSn + s] * w2c[s];
        y2[b * Cn + c] = 1.0f / (1.0f + __expf(-acc));
    }
}

// ---------------- Kernel 3: broadcast channel scale ----------------
__global__ __launch_bounds__(256) void scale_kernel(const float* __restrict__ x,
                                                    const float* __restrict__ y2,
                                                    float* __restrict__ out) {
    const size_t i = (size_t)blockIdx.x * 256 + threadIdx.x;   // float4 index
    const int bc = (int)(i >> 12);                             // i / 4096
    const float g = y2[bc];
    float4 v = ((const float4*)x)[i];
    v.x *= g; v.y *= g; v.z *= g; v.w *= g;
    ((float4*)out)[i] = v;
}

extern "C" void kernel_launch(void* const* d_in, const int* in_sizes, int n_in,
                              void* d_out, int out_size, void* d_ws, size_t ws_size,
                              hipStream_t stream) {
    const float* x  = (const float*)d_in[0];
    const float* w1 = (const float*)d_in[1];
    const float* b1 = (const float*)d_in[2];
    const float* w2 = (const float*)d_in[3];
    const float* b2 = (const float*)d_in[4];
    float* out = (float*)d_out;

    float* y  = (float*)d_ws;           // [B*C]   = 2048 floats
    float* y2 = (float*)d_ws + Bn * Cn; // [B*C]   = 2048 floats

    pool_kernel<<<Bn * Cn, 256, 0, stream>>>(x, y);
    gate_kernel<<<1, 256, 0, stream>>>(y, w1, b1, w2, b2, y2);
    // total float4 elements: 8*256*16384/4 = 8,388,608 → 32768 blocks of 256
    scale_kernel<<<(Bn * Cn * HWn / 4) / 256, 256, 0, stream>>>(x, y2, out);
}